// Round 1
// baseline (1426.982 us; speedup 1.0000x reference)
//
#include <hip/hip_runtime.h>
#include <hip/hip_bf16.h>
#include <math.h>

#define U_CNT   100000
#define NB_CNT  50000
#define D_DIM   256
#define B_CNT   2048
#define L_CNT   50
#define K_SLOT  4
#define HID_DIM 1024
#define TDIM    128
#define NSTEPS  10
#define IN_DIM  1152
#define M_ROWS  (B_CNT*K_SLOT)   // 8192

typedef __hip_bfloat16 bf16;
typedef short bf16x8 __attribute__((ext_vector_type(8)));
typedef float f32x4 __attribute__((ext_vector_type(4)));

typedef const __attribute__((address_space(1))) void GV;
typedef __attribute__((address_space(3))) void LV;

__device__ __forceinline__ void gld_lds16(const void* g, void* l) {
    __builtin_amdgcn_global_load_lds((GV*)g, (LV*)l, 16, 0, 0);
}

__device__ __forceinline__ float wsum(float v) {
#pragma unroll
    for (int m = 32; m >= 1; m >>= 1) v += __shfl_xor(v, m, 64);
    return v;
}
__device__ __forceinline__ float wmax(float v) {
#pragma unroll
    for (int m = 32; m >= 1; m >>= 1) v = fmaxf(v, __shfl_xor(v, m, 64));
    return v;
}

// ---------- small utility kernels ----------

__global__ void k_f32_to_bf16(const float* __restrict__ s, bf16* __restrict__ d, int n) {
    int i = blockIdx.x * blockDim.x + threadIdx.x;
    int stride = gridDim.x * blockDim.x;
    for (; i < n; i += stride) d[i] = __float2bfloat16(s[i]);
}

// d[c][r] = s[r][c]  (s is [R,C] f32, d is [C,R] bf16)
__global__ void k_transpose_bf16(const float* __restrict__ s, bf16* __restrict__ d, int R, int C) {
    int i = blockIdx.x * blockDim.x + threadIdx.x;
    if (i < R * C) {
        int r = i / C, c = i % C;
        d[c * R + r] = __float2bfloat16(s[r * C + c]);
    }
}

// te[t][i] : i<64 -> cos(t*freq_i) ; i>=64 -> sin(t*freq_{i-64})
__global__ void k_te(float* __restrict__ te) {
    int i = threadIdx.x;  // 128
    float freq = expf(-9.210340371976184f * (float)(i & 63) / 64.0f);
    for (int t = 0; t < NSTEPS; t++) {
        float a = (float)t * freq;
        te[t * TDIM + i] = (i < 64) ? cosf(a) : sinf(a);
    }
}

// qbias[k*256+c] = normalize(slot_queries)[k][c] + bus[k*256+c]   (1 block, 256 thr)
__global__ void k_qbias(const float* __restrict__ sq, const float* __restrict__ bus,
                        float* __restrict__ qb) {
    int wave = threadIdx.x >> 6, lane = threadIdx.x & 63;
    f32x4 v = *(const f32x4*)&sq[wave * 256 + lane * 4];
    float ss = v[0]*v[0] + v[1]*v[1] + v[2]*v[2] + v[3]*v[3];
    float inv = 1.0f / fmaxf(sqrtf(wsum(ss)), 1e-12f);
#pragma unroll
    for (int j = 0; j < 4; j++) {
        int c = wave * 256 + lane * 4 + j;
        qb[c] = v[j] * inv + bus[c];
    }
}

// uv = normalize(user_emb[user_idx])  -> f32 and bf16   (grid B, block 64)
__global__ void k_uv(const float* __restrict__ ue, const int* __restrict__ uidx,
                     float* __restrict__ uvf, bf16* __restrict__ uvb) {
    int b = blockIdx.x, lane = threadIdx.x;
    int idx = uidx[b];
    f32x4 v = *(const f32x4*)&ue[(size_t)idx * 256 + lane * 4];
    float ss = v[0]*v[0] + v[1]*v[1] + v[2]*v[2] + v[3]*v[3];
    float inv = 1.0f / fmaxf(sqrtf(wsum(ss)), 1e-12f);
#pragma unroll
    for (int j = 0; j < 4; j++) {
        float x = v[j] * inv;
        uvf[(size_t)b * 256 + lane * 4 + j] = x;
        uvb[(size_t)b * 256 + lane * 4 + j] = __float2bfloat16(x);
    }
}

// in-place row normalize [rows,256]  (grid rows, block 64)
__global__ void k_rownorm(float* __restrict__ x) {
    int r = blockIdx.x, lane = threadIdx.x;
    f32x4 v = *(const f32x4*)&x[(size_t)r * 256 + lane * 4];
    float ss = v[0]*v[0] + v[1]*v[1] + v[2]*v[2] + v[3]*v[3];
    float inv = 1.0f / fmaxf(sqrtf(wsum(ss)), 1e-12f);
#pragma unroll
    for (int j = 0; j < 4; j++) x[(size_t)r * 256 + lane * 4 + j] = v[j] * inv;
}

// feat = [sv, q, sv*q, |sv-q|] bf16   (grid 8192, block 256)
__global__ void k_feat(const float* __restrict__ sv, const float* __restrict__ q,
                       bf16* __restrict__ feat) {
    int m = blockIdx.x, c = threadIdx.x;
    float s = sv[(size_t)m * 256 + c];
    float qq = q[(size_t)m * 256 + c];
    bf16* f = feat + (size_t)m * 1024;
    f[c]       = __float2bfloat16(s);
    f[256 + c] = __float2bfloat16(qq);
    f[512 + c] = __float2bfloat16(s * qq);
    f[768 + c] = __float2bfloat16(fabsf(s - qq));
}

// f = [z, u, z*u, |z-u|, te] bf16   (grid 8192, block 256)
__global__ void k_buildf(const float* __restrict__ z, const float* __restrict__ uv,
                         const float* __restrict__ te, bf16* __restrict__ f) {
    int m = blockIdx.x, c = threadIdx.x;
    int b = m >> 2;
    float zz = z[(size_t)m * 256 + c];
    float uu = uv[(size_t)b * 256 + c];
    bf16* fr = f + (size_t)m * IN_DIM;
    fr[c]        = __float2bfloat16(zz);
    fr[256 + c]  = __float2bfloat16(uu);
    fr[512 + c]  = __float2bfloat16(zz * uu);
    fr[768 + c]  = __float2bfloat16(fabsf(zz - uu));
    if (c < 128) fr[1024 + c] = __float2bfloat16(te[c]);
}

// ---------- MFMA GEMM: C[M,N] = act(A[M,K] @ W[N,K]^T + rowScale[m]*bias[n]) ----------
// m97 structure: 128x128 tile, 4 waves (2x2 of 64x64), BK=32, global_load_lds w16 staging.
template<int RELU, int OUT_BF16>
__global__ __launch_bounds__(256)
void k_gemm_bt(const bf16* __restrict__ A, const bf16* __restrict__ W,
               const float* __restrict__ bias, const float* __restrict__ rowScale,
               float* __restrict__ outF, bf16* __restrict__ outB,
               int M, int N, int K) {
    __shared__ bf16 As[128 * 32];
    __shared__ bf16 Bs[128 * 32];
    const int tid = threadIdx.x;
    const int wave = tid >> 6, lane = tid & 63;
    const int bm = blockIdx.y * 128, bn = blockIdx.x * 128;
    const int wm = (wave >> 1) * 64, wn = (wave & 1) * 64;
    const int sr = lane >> 2;           // staging row within 16-row group
    const int sc = (lane & 3) * 8;      // staging col (bf16 elems)
    const int fr = lane & 15, fk = (lane >> 4) * 8;

    f32x4 acc[4][4] = {};

    for (int k0 = 0; k0 < K; k0 += 32) {
        __syncthreads();
#pragma unroll
        for (int i = 0; i < 2; i++) {
            int rr = 16 * wave + 64 * i + sr;
            const bf16* gA = A + (size_t)(bm + rr) * K + k0 + sc;
            const bf16* gB = W + (size_t)(bn + rr) * K + k0 + sc;
            gld_lds16(gA, &As[(16 * wave + 64 * i) * 32]);
            gld_lds16(gB, &Bs[(16 * wave + 64 * i) * 32]);
        }
        __syncthreads();
        bf16x8 a[4], b[4];
#pragma unroll
        for (int m = 0; m < 4; m++) a[m] = *(const bf16x8*)&As[(wm + m * 16 + fr) * 32 + fk];
#pragma unroll
        for (int n = 0; n < 4; n++) b[n] = *(const bf16x8*)&Bs[(wn + n * 16 + fr) * 32 + fk];
#pragma unroll
        for (int m = 0; m < 4; m++)
#pragma unroll
            for (int n = 0; n < 4; n++)
                acc[m][n] = __builtin_amdgcn_mfma_f32_16x16x32_bf16(a[m], b[n], acc[m][n], 0, 0, 0);
    }

    const int er = lane >> 4;  // 0..3
#pragma unroll
    for (int n = 0; n < 4; n++) {
        int col = bn + wn + n * 16 + fr;
        float bv = bias ? bias[col] : 0.0f;
#pragma unroll
        for (int m = 0; m < 4; m++) {
#pragma unroll
            for (int j = 0; j < 4; j++) {
                int row = bm + wm + m * 16 + er * 4 + j;
                float v = acc[m][n][j] + (rowScale ? rowScale[row] * bv : bv);
                if (RELU) v = fmaxf(v, 0.0f);
                if (OUT_BF16) outB[(size_t)row * N + col] = __float2bfloat16(v);
                else          outF[(size_t)row * N + col] = v;
            }
        }
    }
}

// ---------- fused per-batch attention ----------
// scores[k][l] = (qt[b,k]·obs[l] + q[b,k]·bk)/16 ; masked softmax ; svpre = sum_l attn*obs
__global__ __launch_bounds__(256)
void k_attn(const float* __restrict__ bundle, const int* __restrict__ oidx,
            const int* __restrict__ omask, const float* __restrict__ qt,
            const float* __restrict__ qf, const float* __restrict__ bk,
            bf16* __restrict__ svpre, float* __restrict__ asum) {
    __shared__ float obs[L_CNT][260];
    __shared__ float attn_s[K_SLOT][64];
    __shared__ int valids[64];
    int b = blockIdx.x;
    int tid = threadIdx.x, wave = tid >> 6, lane = tid & 63;

    if (tid < 64) valids[tid] = (tid < L_CNT) ? omask[(size_t)b * L_CNT + tid] : 0;

    // phase 1: gather+normalize observed bundle rows into LDS
    for (int l = wave; l < L_CNT; l += 4) {
        int bi = oidx[(size_t)b * L_CNT + l];
        if (bi < 0) bi = 0;
        f32x4 v = *(const f32x4*)&bundle[(size_t)bi * 256 + lane * 4];
        float ss = v[0]*v[0] + v[1]*v[1] + v[2]*v[2] + v[3]*v[3];
        float inv = 1.0f / fmaxf(sqrtf(wsum(ss)), 1e-12f);
#pragma unroll
        for (int j = 0; j < 4; j++) obs[l][lane * 4 + j] = v[j] * inv;
    }
    __syncthreads();

    // each wave owns one slot k
    int k = wave;
    f32x4 qtv = *(const f32x4*)&qt[((size_t)b * 4 + k) * 256 + lane * 4];
    f32x4 qv  = *(const f32x4*)&qf[((size_t)b * 4 + k) * 256 + lane * 4];
    f32x4 bkv = *(const f32x4*)&bk[lane * 4];
    float qb = wsum(qv[0]*bkv[0] + qv[1]*bkv[1] + qv[2]*bkv[2] + qv[3]*bkv[3]);

    // phase 2: scores (one reduction per l; result kept on lane==l)
    float myscore = -1e30f;
    for (int l = 0; l < L_CNT; l++) {
        f32x4 ov = *(const f32x4*)&obs[l][lane * 4];
        float p = qtv[0]*ov[0] + qtv[1]*ov[1] + qtv[2]*ov[2] + qtv[3]*ov[3];
        float s = wsum(p);
        if (lane == l) myscore = (s + qb) * 0.0625f;
    }

    // phase 3: masked softmax over l (64-lane, lanes>=50 padded)
    bool valid = (lane < L_CNT) && (valids[lane] > 0);
    float s = valid ? myscore : -1e30f;
    float mx = wmax(s);
    float e = (lane < L_CNT) ? expf(s - mx) : 0.0f;
    float sum = wsum(e);
    float a = valid ? e / sum : 0.0f;
    attn_s[k][lane] = a;
    float as = wsum(a);
    if (lane == 0) asum[(size_t)b * 4 + k] = as;

    // phase 4: svpre[k][:] = sum_l attn[l] * obs[l][:]
    f32x4 accv = {0.f, 0.f, 0.f, 0.f};
    for (int l = 0; l < L_CNT; l++) {
        float al = attn_s[k][l];
        f32x4 ov = *(const f32x4*)&obs[l][lane * 4];
        accv[0] += al * ov[0]; accv[1] += al * ov[1];
        accv[2] += al * ov[2]; accv[3] += al * ov[3];
    }
#pragma unroll
    for (int j = 0; j < 4; j++)
        svpre[((size_t)b * 4 + k) * 256 + lane * 4 + j] = __float2bfloat16(accv[j]);
}

// ---------- host ----------

extern "C" void kernel_launch(void* const* d_in, const int* in_sizes, int n_in,
                              void* d_out, int out_size, void* d_ws, size_t ws_size,
                              hipStream_t stream) {
    const float* ue   = (const float*)d_in[0];
    const float* be   = (const float*)d_in[1];
    const float* sq   = (const float*)d_in[2];
    const float* Wk   = (const float*)d_in[3];
    const float* bk   = (const float*)d_in[4];
    const float* Wv   = (const float*)d_in[5];
    const float* bv   = (const float*)d_in[6];
    const float* Wus  = (const float*)d_in[7];
    const float* bus  = (const float*)d_in[8];
    const float* Wf1  = (const float*)d_in[9];
    const float* bf1  = (const float*)d_in[10];
    const float* Wf2  = (const float*)d_in[11];
    const float* bf2  = (const float*)d_in[12];
    const float* Wd1  = (const float*)d_in[13];
    const float* bd1  = (const float*)d_in[14];
    const float* Wd2  = (const float*)d_in[15];
    const float* bd2  = (const float*)d_in[16];
    const float* Wd3  = (const float*)d_in[17];
    const float* bd3  = (const float*)d_in[18];
    const int* uidx   = (const int*)d_in[19];
    const int* oidx   = (const int*)d_in[20];
    const int* omask  = (const int*)d_in[21];
    float* out = (float*)d_out;

    char* ws = (char*)d_ws;
    size_t off = 0;
    auto alloc = [&](size_t bytes) -> void* {
        void* p = ws + off;
        off += (bytes + 255) & ~(size_t)255;
        return p;
    };

    float* uvf   = (float*)alloc((size_t)B_CNT * 256 * 4);
    bf16*  uvb   = (bf16*) alloc((size_t)B_CNT * 256 * 2);
    float* qbias = (float*)alloc(1024 * 4);
    float* qf    = (float*)alloc((size_t)B_CNT * 1024 * 4);   // 8 MB   } reused as fbuf
    bf16*  qb16  = (bf16*) alloc((size_t)B_CNT * 1024 * 2);   // 4 MB   } in diffusion
    float* qt    = (float*)alloc((size_t)M_ROWS * 256 * 4);   // 8 MB   }
    bf16*  svpre = (bf16*) alloc((size_t)M_ROWS * 256 * 2);
    float* asum  = (float*)alloc((size_t)M_ROWS * 4);
    float* sv    = (float*)alloc((size_t)M_ROWS * 256 * 4);
    bf16*  feat  = (bf16*) alloc((size_t)M_ROWS * 1024 * 2);  // reused as h1
    bf16*  henc  = (bf16*) alloc((size_t)M_ROWS * 1024 * 2);  // reused as h2
    float* zbuf  = (float*)alloc((size_t)M_ROWS * 256 * 4);
    float* teb   = (float*)alloc(NSTEPS * TDIM * 4);
    bf16*  wusB  = (bf16*) alloc((size_t)1024 * 256 * 2);
    bf16*  wkT   = (bf16*) alloc((size_t)256 * 256 * 2);
    bf16*  wvB   = (bf16*) alloc((size_t)256 * 256 * 2);
    bf16*  wf1B  = (bf16*) alloc((size_t)1024 * 1024 * 2);
    bf16*  wf2B  = (bf16*) alloc((size_t)256 * 1024 * 2);
    bf16*  wd1B  = (bf16*) alloc((size_t)1024 * 1152 * 2);
    bf16*  wd2B  = (bf16*) alloc((size_t)1024 * 1024 * 2);
    bf16*  wd3B  = (bf16*) alloc((size_t)256 * 1024 * 2);
    // diffusion-phase aliases (encoder buffers are dead by then)
    bf16* fbuf = (bf16*)qf;   // needs 18.9 MB; qf+qb16+qt region = 20 MB contiguous
    bf16* h1   = feat;
    bf16* h2   = henc;

    auto cvt = [&](const float* s, bf16* d, int n) {
        int blocks = (n + 255) / 256;
        if (blocks > 2048) blocks = 2048;
        k_f32_to_bf16<<<blocks, 256, 0, stream>>>(s, d, n);
    };

    // weight prep (inputs re-poisoned every call -> redo every launch)
    cvt(Wus, wusB, 1024 * 256);
    k_transpose_bf16<<<256, 256, 0, stream>>>(Wk, wkT, 256, 256);
    cvt(Wv,  wvB,  256 * 256);
    cvt(Wf1, wf1B, 1024 * 1024);
    cvt(Wf2, wf2B, 256 * 1024);
    cvt(Wd1, wd1B, 1024 * 1152);
    cvt(Wd2, wd2B, 1024 * 1024);
    cvt(Wd3, wd3B, 256 * 1024);
    k_te<<<1, 128, 0, stream>>>(teb);
    k_qbias<<<1, 256, 0, stream>>>(sq, bus, qbias);

    // encoder
    k_uv<<<B_CNT, 64, 0, stream>>>(ue, uidx, uvf, uvb);
    // q[B, K*D] = uv @ Wus^T + (qn+bus)
    k_gemm_bt<0, 0><<<dim3(1024 / 128, 2048 / 128), 256, 0, stream>>>(
        uvb, wusB, qbias, nullptr, qf, nullptr, 2048, 1024, 256);
    cvt(qf, qb16, 2048 * 1024);
    // qt[(b,k), d] = q @ Wk   (W operand = Wk^T)
    k_gemm_bt<0, 0><<<dim3(256 / 128, M_ROWS / 128), 256, 0, stream>>>(
        qb16, wkT, nullptr, nullptr, qt, nullptr, M_ROWS, 256, 256);
    k_attn<<<B_CNT, 256, 0, stream>>>(be, oidx, omask, qt, qf, bk, svpre, asum);
    // sv = svpre @ Wv^T + asum*bv
    k_gemm_bt<0, 0><<<dim3(2, 64), 256, 0, stream>>>(
        svpre, wvB, bv, asum, sv, nullptr, M_ROWS, 256, 256);
    k_feat<<<M_ROWS, 256, 0, stream>>>(sv, qf, feat);
    k_gemm_bt<1, 1><<<dim3(8, 64), 256, 0, stream>>>(
        feat, wf1B, bf1, nullptr, nullptr, henc, M_ROWS, 1024, 1024);
    k_gemm_bt<0, 0><<<dim3(2, 64), 256, 0, stream>>>(
        henc, wf2B, bf2, nullptr, zbuf, nullptr, M_ROWS, 256, 1024);
    k_rownorm<<<M_ROWS, 64, 0, stream>>>(zbuf);

    // diffusion: steps 9..0
    for (int t = NSTEPS - 1; t >= 0; t--) {
        k_buildf<<<M_ROWS, 256, 0, stream>>>(zbuf, uvf, teb + t * TDIM, fbuf);
        k_gemm_bt<1, 1><<<dim3(8, 64), 256, 0, stream>>>(
            fbuf, wd1B, bd1, nullptr, nullptr, h1, M_ROWS, 1024, IN_DIM);
        k_gemm_bt<1, 1><<<dim3(8, 64), 256, 0, stream>>>(
            h1, wd2B, bd2, nullptr, nullptr, h2, M_ROWS, 1024, 1024);
        float* zo = (t == 0) ? out : zbuf;
        k_gemm_bt<0, 0><<<dim3(2, 64), 256, 0, stream>>>(
            h2, wd3B, bd3, nullptr, zo, nullptr, M_ROWS, 256, 1024);
    }
}

// Round 2
// 1107.837 us; speedup vs baseline: 1.2881x; 1.2881x over previous
//
#include <hip/hip_runtime.h>
#include <hip/hip_bf16.h>
#include <math.h>

#define U_CNT   100000
#define NB_CNT  50000
#define D_DIM   256
#define B_CNT   2048
#define L_CNT   50
#define K_SLOT  4
#define HID_DIM 1024
#define TDIM    128
#define NSTEPS  10
#define IN_DIM  1152
#define M_ROWS  (B_CNT*K_SLOT)   // 8192

typedef __hip_bfloat16 bf16;
typedef short bf16x8 __attribute__((ext_vector_type(8)));
typedef float f32x4 __attribute__((ext_vector_type(4)));

typedef const __attribute__((address_space(1))) void GV;
typedef __attribute__((address_space(3))) void LV;

__device__ __forceinline__ void gld_lds16(const void* g, void* l) {
    __builtin_amdgcn_global_load_lds((GV*)g, (LV*)l, 16, 0, 0);
}

__device__ __forceinline__ float wsum(float v) {
#pragma unroll
    for (int m = 32; m >= 1; m >>= 1) v += __shfl_xor(v, m, 64);
    return v;
}
__device__ __forceinline__ float wmax(float v) {
#pragma unroll
    for (int m = 32; m >= 1; m >>= 1) v = fmaxf(v, __shfl_xor(v, m, 64));
    return v;
}

__device__ __forceinline__ void sbar() { __builtin_amdgcn_s_barrier(); }
__device__ __forceinline__ void lgkm0() {
    asm volatile("s_waitcnt lgkmcnt(0)" ::: "memory");
    __builtin_amdgcn_sched_barrier(0);
}
#define VMCNT(n) do { asm volatile("s_waitcnt vmcnt(" #n ")" ::: "memory"); \
                      __builtin_amdgcn_sched_barrier(0); } while (0)

// ---------- small utility kernels ----------

__global__ void k_f32_to_bf16(const float* __restrict__ s, bf16* __restrict__ d, int n) {
    int i = blockIdx.x * blockDim.x + threadIdx.x;
    int stride = gridDim.x * blockDim.x;
    for (; i < n; i += stride) d[i] = __float2bfloat16(s[i]);
}

// d[c][r] = s[r][c]  (s is [R,C] f32, d is [C,R] bf16)
__global__ void k_transpose_bf16(const float* __restrict__ s, bf16* __restrict__ d, int R, int C) {
    int i = blockIdx.x * blockDim.x + threadIdx.x;
    if (i < R * C) {
        int r = i / C, c = i % C;
        d[c * R + r] = __float2bfloat16(s[r * C + c]);
    }
}

// te bf16 table [NSTEPS][TDIM]: i<64 -> cos(t*freq_i) ; i>=64 -> sin(t*freq_{i-64})
__global__ void k_te(bf16* __restrict__ te) {
    int i = threadIdx.x;  // 128
    float freq = expf(-9.210340371976184f * (float)(i & 63) / 64.0f);
    for (int t = 0; t < NSTEPS; t++) {
        float a = (float)t * freq;
        te[t * TDIM + i] = __float2bfloat16((i < 64) ? cosf(a) : sinf(a));
    }
}

// qbias[k*256+c] = normalize(slot_queries)[k][c] + bus[k*256+c]   (1 block, 256 thr)
__global__ void k_qbias(const float* __restrict__ sq, const float* __restrict__ bus,
                        float* __restrict__ qb) {
    int wave = threadIdx.x >> 6, lane = threadIdx.x & 63;
    f32x4 v = *(const f32x4*)&sq[wave * 256 + lane * 4];
    float ss = v[0]*v[0] + v[1]*v[1] + v[2]*v[2] + v[3]*v[3];
    float inv = 1.0f / fmaxf(sqrtf(wsum(ss)), 1e-12f);
#pragma unroll
    for (int j = 0; j < 4; j++) {
        int c = wave * 256 + lane * 4 + j;
        qb[c] = v[j] * inv + bus[c];
    }
}

// uv = normalize(user_emb[user_idx])  -> f32 and bf16   (grid B, block 64)
__global__ void k_uv(const float* __restrict__ ue, const int* __restrict__ uidx,
                     float* __restrict__ uvf, bf16* __restrict__ uvb) {
    int b = blockIdx.x, lane = threadIdx.x;
    int idx = uidx[b];
    f32x4 v = *(const f32x4*)&ue[(size_t)idx * 256 + lane * 4];
    float ss = v[0]*v[0] + v[1]*v[1] + v[2]*v[2] + v[3]*v[3];
    float inv = 1.0f / fmaxf(sqrtf(wsum(ss)), 1e-12f);
#pragma unroll
    for (int j = 0; j < 4; j++) {
        float x = v[j] * inv;
        uvf[(size_t)b * 256 + lane * 4 + j] = x;
        uvb[(size_t)b * 256 + lane * 4 + j] = __float2bfloat16(x);
    }
}

// in-place row normalize [rows,256]  (grid rows, block 64)
__global__ void k_rownorm(float* __restrict__ x) {
    int r = blockIdx.x, lane = threadIdx.x;
    f32x4 v = *(const f32x4*)&x[(size_t)r * 256 + lane * 4];
    float ss = v[0]*v[0] + v[1]*v[1] + v[2]*v[2] + v[3]*v[3];
    float inv = 1.0f / fmaxf(sqrtf(wsum(ss)), 1e-12f);
#pragma unroll
    for (int j = 0; j < 4; j++) x[(size_t)r * 256 + lane * 4 + j] = v[j] * inv;
}

// feat = [sv, q, sv*q, |sv-q|] bf16   (grid 8192, block 256)
__global__ void k_feat(const float* __restrict__ sv, const float* __restrict__ q,
                       bf16* __restrict__ feat) {
    int m = blockIdx.x, c = threadIdx.x;
    float s = sv[(size_t)m * 256 + c];
    float qq = q[(size_t)m * 256 + c];
    bf16* f = feat + (size_t)m * 1024;
    f[c]       = __float2bfloat16(s);
    f[256 + c] = __float2bfloat16(qq);
    f[512 + c] = __float2bfloat16(s * qq);
    f[768 + c] = __float2bfloat16(fabsf(s - qq));
}

// f = [z, u, z*u, |z-u|, te] bf16   (grid 8192, block 256)  — used once (step 9 input)
__global__ void k_buildf(const float* __restrict__ z, const float* __restrict__ uv,
                         const bf16* __restrict__ te, bf16* __restrict__ f) {
    int m = blockIdx.x, c = threadIdx.x;
    int b = m >> 2;
    float zz = z[(size_t)m * 256 + c];
    float uu = uv[(size_t)b * 256 + c];
    bf16* fr = f + (size_t)m * IN_DIM;
    fr[c]        = __float2bfloat16(zz);
    fr[256 + c]  = __float2bfloat16(uu);
    fr[512 + c]  = __float2bfloat16(zz * uu);
    fr[768 + c]  = __float2bfloat16(fabsf(zz - uu));
    if (c < 128) fr[1024 + c] = te[c];
}

// ---------- legacy MFMA GEMM (2-barrier, m97 structure) — small shapes ----------
// C[M,N] = A[M,K] @ W[N,K]^T + rowScale[m]*bias[n]  (f32 out)
__global__ __launch_bounds__(256)
void k_gemm_bt(const bf16* __restrict__ A, const bf16* __restrict__ W,
               const float* __restrict__ bias, const float* __restrict__ rowScale,
               float* __restrict__ outF, int M, int N, int K) {
    __shared__ bf16 As[128 * 32];
    __shared__ bf16 Bs[128 * 32];
    const int tid = threadIdx.x;
    const int wave = tid >> 6, lane = tid & 63;
    const int bm = blockIdx.y * 128, bn = blockIdx.x * 128;
    const int wm = (wave >> 1) * 64, wn = (wave & 1) * 64;
    const int sr = lane >> 2;
    const int sc = (lane & 3) * 8;
    const int fr = lane & 15, fk = (lane >> 4) * 8;

    f32x4 acc[4][4] = {};

    for (int k0 = 0; k0 < K; k0 += 32) {
        __syncthreads();
#pragma unroll
        for (int i = 0; i < 2; i++) {
            int rr = 16 * wave + 64 * i + sr;
            const bf16* gA = A + (size_t)(bm + rr) * K + k0 + sc;
            const bf16* gB = W + (size_t)(bn + rr) * K + k0 + sc;
            gld_lds16(gA, &As[(16 * wave + 64 * i) * 32]);
            gld_lds16(gB, &Bs[(16 * wave + 64 * i) * 32]);
        }
        __syncthreads();
        bf16x8 a[4], b[4];
#pragma unroll
        for (int m = 0; m < 4; m++) a[m] = *(const bf16x8*)&As[(wm + m * 16 + fr) * 32 + fk];
#pragma unroll
        for (int n = 0; n < 4; n++) b[n] = *(const bf16x8*)&Bs[(wn + n * 16 + fr) * 32 + fk];
#pragma unroll
        for (int m = 0; m < 4; m++)
#pragma unroll
            for (int n = 0; n < 4; n++)
                acc[m][n] = __builtin_amdgcn_mfma_f32_16x16x32_bf16(a[m], b[n], acc[m][n], 0, 0, 0);
    }

    const int er = lane >> 4;
#pragma unroll
    for (int n = 0; n < 4; n++) {
        int col = bn + wn + n * 16 + fr;
        float bv = bias ? bias[col] : 0.0f;
#pragma unroll
        for (int m = 0; m < 4; m++) {
#pragma unroll
            for (int j = 0; j < 4; j++) {
                int row = bm + wm + m * 16 + er * 4 + j;
                float v = acc[m][n][j] + (rowScale ? rowScale[row] * bv : bv);
                outF[(size_t)row * N + col] = v;
            }
        }
    }
}

// ---------- pipelined MFMA GEMM (T2+T3+T4+T5): 128x128 tile, BK=64, 4 waves ----------
// 4 phases/K-tile; counted vmcnt(8) once per tile; staging 2 tiles ahead (other dbuf);
// XOR swizzle byte^=(row&7)<<4 applied on gld source + ds_read (both-sides involution).
// MODE 0: f32 out (+bias). MODE 1: relu -> bf16. MODE 2: z=acc+bias -> fused buildf
// (writes [z,u,z*u,|z-u|] segments of fbuf; bn==0 blocks also copy te).
template<int MODE>
__global__ __launch_bounds__(256, 2)
void k_gemm8(const bf16* __restrict__ A, const bf16* __restrict__ W,
             const float* __restrict__ bias,
             float* __restrict__ outF, bf16* __restrict__ outB,
             const float* __restrict__ uvf, const bf16* __restrict__ te,
             int M, int N, int K) {
    __shared__ bf16 As[2][128][64];   // 32 KB
    __shared__ bf16 Bs[2][128][64];   // 32 KB
    const int tid = threadIdx.x;
    const int wid = tid >> 6, lane = tid & 63;
    const int wm = wid >> 1, wn = wid & 1;          // 2x2 waves, wave tile 64x64
    const int bm = blockIdx.y * 128, bn = blockIdx.x * 128;
    const int fr = lane & 15, fk8 = (lane >> 4) * 8;
    const int srow = lane >> 3;                      // 0..7 (row within 8-row gld block)
    const int scol = ((lane & 7) ^ srow) * 8;        // pre-swizzled source col (elems)
    const int swz = (fr & 7) * 8;                    // read-side swizzle (elems)
    const int NT = K >> 6;

    // Each wave stages 32 rows (4 gld x 8 rows x 1KB) of each tile.
    auto stageA = [&](int t) {
        const int buf = t & 1;
        const bf16* src = A + (size_t)(bm + wid * 32 + srow) * K + t * 64 + scol;
#pragma unroll
        for (int i = 0; i < 4; i++)
            gld_lds16(src + (size_t)i * 8 * K, &As[buf][wid * 32 + i * 8][0]);
    };
    auto stageB = [&](int t) {
        const int buf = t & 1;
        const bf16* src = W + (size_t)(bn + wid * 32 + srow) * K + t * 64 + scol;
#pragma unroll
        for (int i = 0; i < 4; i++)
            gld_lds16(src + (size_t)i * 8 * K, &Bs[buf][wid * 32 + i * 8][0]);
    };

    f32x4 acc[4][4] = {};

    // prologue: tiles 0 and 1 (issue order per tile: B then A — matches loop)
    stageB(0); stageA(0);
    stageB(1); stageA(1);
    VMCNT(8);              // tile 0 complete (tile 1's 8 loads in flight)
    sbar();

    for (int t = 0; t < NT; t++) {
        const int buf = t & 1;
        bf16x8 a0[2][2], a1[2][2], b0[2][2], b1[2][2];

        // ---- P1: read A[Mf0,1], B[Nf0,1]; MFMA Q(0,0) ----
#pragma unroll
        for (int m = 0; m < 2; m++)
#pragma unroll
            for (int s = 0; s < 2; s++)
                a0[m][s] = *(const bf16x8*)&As[buf][wm * 64 + m * 16 + fr][(s * 32 + fk8) ^ swz];
#pragma unroll
        for (int n = 0; n < 2; n++)
#pragma unroll
            for (int s = 0; s < 2; s++)
                b0[n][s] = *(const bf16x8*)&Bs[buf][wn * 64 + n * 16 + fr][(s * 32 + fk8) ^ swz];
        sbar(); lgkm0();
        __builtin_amdgcn_s_setprio(1);
#pragma unroll
        for (int m = 0; m < 2; m++)
#pragma unroll
            for (int n = 0; n < 2; n++)
#pragma unroll
                for (int s = 0; s < 2; s++)
                    acc[m][n] = __builtin_amdgcn_mfma_f32_16x16x32_bf16(a0[m][s], b0[n][s], acc[m][n], 0, 0, 0);
        __builtin_amdgcn_s_setprio(0);
        sbar();

        // ---- P2: read B[Nf2,3]; MFMA Q(0,1) ----
#pragma unroll
        for (int n = 0; n < 2; n++)
#pragma unroll
            for (int s = 0; s < 2; s++)
                b1[n][s] = *(const bf16x8*)&Bs[buf][wn * 64 + (n + 2) * 16 + fr][(s * 32 + fk8) ^ swz];
        sbar(); lgkm0();
        __builtin_amdgcn_s_setprio(1);
#pragma unroll
        for (int m = 0; m < 2; m++)
#pragma unroll
            for (int n = 0; n < 2; n++)
#pragma unroll
                for (int s = 0; s < 2; s++)
                    acc[m][n + 2] = __builtin_amdgcn_mfma_f32_16x16x32_bf16(a0[m][s], b1[n][s], acc[m][n + 2], 0, 0, 0);
        __builtin_amdgcn_s_setprio(0);
        sbar();

        // ---- P3: read A[Mf2,3]; stage B(t+2) (B reads of this tile done end-P2); MFMA Q(1,1) ----
#pragma unroll
        for (int m = 0; m < 2; m++)
#pragma unroll
            for (int s = 0; s < 2; s++)
                a1[m][s] = *(const bf16x8*)&As[buf][wm * 64 + (m + 2) * 16 + fr][(s * 32 + fk8) ^ swz];
        if (t + 2 < NT) stageB(t + 2);
        sbar(); lgkm0();
        __builtin_amdgcn_s_setprio(1);
#pragma unroll
        for (int m = 0; m < 2; m++)
#pragma unroll
            for (int n = 0; n < 2; n++)
#pragma unroll
                for (int s = 0; s < 2; s++)
                    acc[m + 2][n + 2] = __builtin_amdgcn_mfma_f32_16x16x32_bf16(a1[m][s], b1[n][s], acc[m + 2][n + 2], 0, 0, 0);
        __builtin_amdgcn_s_setprio(0);
        sbar();

        // ---- P4: stage A(t+2) (A reads done end-P3); counted vmcnt; MFMA Q(1,0) ----
        if (t + 2 < NT) {
            stageA(t + 2);
            VMCNT(8);      // tile t+1 (oldest 8 loads) complete; t+2's 8 in flight
        } else if (t + 2 == NT) {
            VMCNT(0);      // next tile is the last staged one — drain
        }
        sbar(); lgkm0();
        __builtin_amdgcn_s_setprio(1);
#pragma unroll
        for (int m = 0; m < 2; m++)
#pragma unroll
            for (int n = 0; n < 2; n++)
#pragma unroll
                for (int s = 0; s < 2; s++)
                    acc[m + 2][n] = __builtin_amdgcn_mfma_f32_16x16x32_bf16(a1[m][s], b0[n][s], acc[m + 2][n], 0, 0, 0);
        __builtin_amdgcn_s_setprio(0);
        sbar();
    }

    const int er = lane >> 4;
#pragma unroll
    for (int n = 0; n < 4; n++) {
        const int col = bn + wn * 64 + n * 16 + fr;
        const float bv = bias[col];
#pragma unroll
        for (int m = 0; m < 4; m++) {
#pragma unroll
            for (int j = 0; j < 4; j++) {
                const int row = bm + wm * 64 + m * 16 + er * 4 + j;
                float v = acc[m][n][j] + bv;
                if (MODE == 1) {
                    v = fmaxf(v, 0.0f);
                    outB[(size_t)row * N + col] = __float2bfloat16(v);
                } else if (MODE == 0) {
                    outF[(size_t)row * N + col] = v;
                } else {
                    const float u = uvf[(size_t)(row >> 2) * 256 + col];
                    bf16* f = outB + (size_t)row * IN_DIM;
                    f[col]       = __float2bfloat16(v);
                    f[256 + col] = __float2bfloat16(u);
                    f[512 + col] = __float2bfloat16(v * u);
                    f[768 + col] = __float2bfloat16(fabsf(v - u));
                }
            }
        }
    }
    if (MODE == 2 && blockIdx.x == 0) {
        // copy te (128 bf16) into rows bm..bm+127: thread -> row tid>>1, half tid&1
        const int r = bm + (tid >> 1);
        const bf16* tesrc = te + (tid & 1) * 64;
        bf16* dst = outB + (size_t)r * IN_DIM + 1024 + (tid & 1) * 64;
#pragma unroll
        for (int j = 0; j < 8; j++)
            *(bf16x8*)&dst[j * 8] = *(const bf16x8*)&tesrc[j * 8];
    }
}

// ---------- fused per-batch attention ----------
__global__ __launch_bounds__(256)
void k_attn(const float* __restrict__ bundle, const int* __restrict__ oidx,
            const int* __restrict__ omask, const float* __restrict__ qt,
            const float* __restrict__ qf, const float* __restrict__ bk,
            bf16* __restrict__ svpre, float* __restrict__ asum) {
    __shared__ float obs[L_CNT][260];
    __shared__ float qts[K_SLOT][256];
    __shared__ float attn_s[K_SLOT][64];
    __shared__ int valids[64];
    int b = blockIdx.x;
    int tid = threadIdx.x, wave = tid >> 6, lane = tid & 63;

    if (tid < 64) valids[tid] = (tid < L_CNT) ? omask[(size_t)b * L_CNT + tid] : 0;

    // stage this wave's qt row into LDS (broadcast-read later)
    {
        f32x4 v = *(const f32x4*)&qt[((size_t)b * 4 + wave) * 256 + lane * 4];
        *(f32x4*)&qts[wave][lane * 4] = v;
    }

    // phase 1: gather+normalize observed bundle rows (issue all loads first)
    int bi[13];
    f32x4 rr[13];
#pragma unroll
    for (int i = 0; i < 13; i++) {
        int l = wave + 4 * i;
        if (l < L_CNT) { int x = oidx[(size_t)b * L_CNT + l]; bi[i] = x < 0 ? 0 : x; }
    }
#pragma unroll
    for (int i = 0; i < 13; i++) {
        int l = wave + 4 * i;
        if (l < L_CNT) rr[i] = *(const f32x4*)&bundle[(size_t)bi[i] * 256 + lane * 4];
    }
#pragma unroll
    for (int i = 0; i < 13; i++) {
        int l = wave + 4 * i;
        if (l < L_CNT) {
            f32x4 v = rr[i];
            float ss = v[0]*v[0] + v[1]*v[1] + v[2]*v[2] + v[3]*v[3];
            float inv = 1.0f / fmaxf(sqrtf(wsum(ss)), 1e-12f);
#pragma unroll
            for (int j = 0; j < 4; j++) obs[l][lane * 4 + j] = v[j] * inv;
        }
    }
    __syncthreads();

    int k = wave;
    // bias dot: q[b,k] . bk
    f32x4 qv  = *(const f32x4*)&qf[((size_t)b * 4 + k) * 256 + lane * 4];
    f32x4 bkv = *(const f32x4*)&bk[lane * 4];
    float qb = wsum(qv[0]*bkv[0] + qv[1]*bkv[1] + qv[2]*bkv[2] + qv[3]*bkv[3]);

    // phase 2: lane l owns score l (parallel dots; qts read is lane-uniform broadcast)
    float dot = 0.0f;
    if (lane < L_CNT) {
#pragma unroll 8
        for (int j = 0; j < 64; j++) {
            f32x4 o  = *(const f32x4*)&obs[lane][j * 4];
            f32x4 qq = *(const f32x4*)&qts[k][j * 4];
            dot += o[0]*qq[0] + o[1]*qq[1] + o[2]*qq[2] + o[3]*qq[3];
        }
    }
    float sc = (dot + qb) * 0.0625f;

    // phase 3: masked softmax over l
    bool valid = (lane < L_CNT) && (valids[lane] > 0);
    float s = valid ? sc : -1e30f;
    float mx = wmax(s);
    float e = (lane < L_CNT) ? expf(s - mx) : 0.0f;
    float sum = wsum(e);
    float a = valid ? e / sum : 0.0f;
    attn_s[k][lane] = a;
    float as = wsum(a);
    if (lane == 0) asum[(size_t)b * 4 + k] = as;

    // phase 4: svpre[k][:] = sum_l attn[l] * obs[l][:]
    f32x4 accv = {0.f, 0.f, 0.f, 0.f};
    for (int l = 0; l < L_CNT; l++) {
        float al = attn_s[k][l];
        f32x4 ov = *(const f32x4*)&obs[l][lane * 4];
        accv[0] += al * ov[0]; accv[1] += al * ov[1];
        accv[2] += al * ov[2]; accv[3] += al * ov[3];
    }
#pragma unroll
    for (int j = 0; j < 4; j++)
        svpre[((size_t)b * 4 + k) * 256 + lane * 4 + j] = __float2bfloat16(accv[j]);
}

// ---------- host ----------

extern "C" void kernel_launch(void* const* d_in, const int* in_sizes, int n_in,
                              void* d_out, int out_size, void* d_ws, size_t ws_size,
                              hipStream_t stream) {
    const float* ue   = (const float*)d_in[0];
    const float* be   = (const float*)d_in[1];
    const float* sq   = (const float*)d_in[2];
    const float* Wk   = (const float*)d_in[3];
    const float* bk   = (const float*)d_in[4];
    const float* Wv   = (const float*)d_in[5];
    const float* bv   = (const float*)d_in[6];
    const float* Wus  = (const float*)d_in[7];
    const float* bus  = (const float*)d_in[8];
    const float* Wf1  = (const float*)d_in[9];
    const float* bf1  = (const float*)d_in[10];
    const float* Wf2  = (const float*)d_in[11];
    const float* bf2  = (const float*)d_in[12];
    const float* Wd1  = (const float*)d_in[13];
    const float* bd1  = (const float*)d_in[14];
    const float* Wd2  = (const float*)d_in[15];
    const float* bd2  = (const float*)d_in[16];
    const float* Wd3  = (const float*)d_in[17];
    const float* bd3  = (const float*)d_in[18];
    const int* uidx   = (const int*)d_in[19];
    const int* oidx   = (const int*)d_in[20];
    const int* omask  = (const int*)d_in[21];
    float* out = (float*)d_out;

    char* ws = (char*)d_ws;
    size_t off = 0;
    auto alloc = [&](size_t bytes) -> void* {
        void* p = ws + off;
        off += (bytes + 255) & ~(size_t)255;
        return p;
    };

    float* uvf   = (float*)alloc((size_t)B_CNT * 256 * 4);
    bf16*  uvb   = (bf16*) alloc((size_t)B_CNT * 256 * 2);
    float* qbias = (float*)alloc(1024 * 4);
    float* qf    = (float*)alloc((size_t)B_CNT * 1024 * 4);   // } reused as fbuf
    bf16*  qb16  = (bf16*) alloc((size_t)B_CNT * 1024 * 2);   // } in diffusion
    float* qt    = (float*)alloc((size_t)M_ROWS * 256 * 4);   // }
    bf16*  svpre = (bf16*) alloc((size_t)M_ROWS * 256 * 2);
    float* asum  = (float*)alloc((size_t)M_ROWS * 4);
    float* sv    = (float*)alloc((size_t)M_ROWS * 256 * 4);
    bf16*  feat  = (bf16*) alloc((size_t)M_ROWS * 1024 * 2);  // reused as h1
    bf16*  henc  = (bf16*) alloc((size_t)M_ROWS * 1024 * 2);  // reused as h2
    float* zbuf  = (float*)alloc((size_t)M_ROWS * 256 * 4);
    bf16*  teb   = (bf16*) alloc(NSTEPS * TDIM * 2);
    bf16*  wusB  = (bf16*) alloc((size_t)1024 * 256 * 2);
    bf16*  wkT   = (bf16*) alloc((size_t)256 * 256 * 2);
    bf16*  wvB   = (bf16*) alloc((size_t)256 * 256 * 2);
    bf16*  wf1B  = (bf16*) alloc((size_t)1024 * 1024 * 2);
    bf16*  wf2B  = (bf16*) alloc((size_t)256 * 1024 * 2);
    bf16*  wd1B  = (bf16*) alloc((size_t)1024 * 1152 * 2);
    bf16*  wd2B  = (bf16*) alloc((size_t)1024 * 1024 * 2);
    bf16*  wd3B  = (bf16*) alloc((size_t)256 * 1024 * 2);
    // diffusion-phase aliases (encoder buffers dead by then)
    bf16* fbuf = (bf16*)qf;   // 18.9 MB needed; qf+qb16+qt region = 20 MB contiguous
    bf16* h1   = feat;
    bf16* h2   = henc;

    auto cvt = [&](const float* s, bf16* d, int n) {
        int blocks = (n + 255) / 256;
        if (blocks > 2048) blocks = 2048;
        k_f32_to_bf16<<<blocks, 256, 0, stream>>>(s, d, n);
    };

    // weight prep
    cvt(Wus, wusB, 1024 * 256);
    k_transpose_bf16<<<256, 256, 0, stream>>>(Wk, wkT, 256, 256);
    cvt(Wv,  wvB,  256 * 256);
    cvt(Wf1, wf1B, 1024 * 1024);
    cvt(Wf2, wf2B, 256 * 1024);
    cvt(Wd1, wd1B, 1024 * 1152);
    cvt(Wd2, wd2B, 1024 * 1024);
    cvt(Wd3, wd3B, 256 * 1024);
    k_te<<<1, 128, 0, stream>>>(teb);
    k_qbias<<<1, 256, 0, stream>>>(sq, bus, qbias);

    // encoder
    k_uv<<<B_CNT, 64, 0, stream>>>(ue, uidx, uvf, uvb);
    // q[B, K*D] = uv @ Wus^T + (qn+bus)
    k_gemm_bt<<<dim3(8, 16), 256, 0, stream>>>(uvb, wusB, qbias, nullptr, qf, 2048, 1024, 256);
    cvt(qf, qb16, 2048 * 1024);
    // qt[(b,k), d] = q @ Wk
    k_gemm_bt<<<dim3(2, 64), 256, 0, stream>>>(qb16, wkT, nullptr, nullptr, qt, M_ROWS, 256, 256);
    k_attn<<<B_CNT, 256, 0, stream>>>(be, oidx, omask, qt, qf, bk, svpre, asum);
    // sv = svpre @ Wv^T + asum*bv
    k_gemm_bt<<<dim3(2, 64), 256, 0, stream>>>(svpre, wvB, bv, asum, sv, M_ROWS, 256, 256);
    k_feat<<<M_ROWS, 256, 0, stream>>>(sv, qf, feat);
    k_gemm8<1><<<dim3(8, 64), 256, 0, stream>>>(feat, wf1B, bf1, nullptr, henc, nullptr, nullptr,
                                                M_ROWS, 1024, 1024);
    k_gemm8<0><<<dim3(2, 64), 256, 0, stream>>>(henc, wf2B, bf2, zbuf, nullptr, nullptr, nullptr,
                                                M_ROWS, 256, 1024);
    k_rownorm<<<M_ROWS, 64, 0, stream>>>(zbuf);
    k_buildf<<<M_ROWS, 256, 0, stream>>>(zbuf, uvf, teb + 9 * TDIM, fbuf);

    // diffusion: steps 9..0 ; Wd3 epilogue fuses next step's feature build
    for (int t = NSTEPS - 1; t >= 0; t--) {
        k_gemm8<1><<<dim3(8, 64), 256, 0, stream>>>(fbuf, wd1B, bd1, nullptr, h1, nullptr, nullptr,
                                                    M_ROWS, 1024, IN_DIM);
        k_gemm8<1><<<dim3(8, 64), 256, 0, stream>>>(h1, wd2B, bd2, nullptr, h2, nullptr, nullptr,
                                                    M_ROWS, 1024, 1024);
        if (t > 0) {
            k_gemm8<2><<<dim3(2, 64), 256, 0, stream>>>(h2, wd3B, bd3, nullptr, fbuf, uvf,
                                                        teb + (t - 1) * TDIM, M_ROWS, 256, 1024);
        } else {
            k_gemm8<0><<<dim3(2, 64), 256, 0, stream>>>(h2, wd3B, bd3, out, nullptr, nullptr, nullptr,
                                                        M_ROWS, 256, 1024);
        }
    }
}